// Round 7
// baseline (320.217 us; speedup 1.0000x reference)
//
#include <hip/hip_runtime.h>
#include <cstdint>
#include <cstddef>

// Problem: B=4, S=4096, HID=1024, H=16, DH=64
//   qkv = query @ W^T + b    (M=16384, N=3072, K=1024)
//   per-position (b,s): scores = q(16x64) @ k^T /8 + mask(16x16); softmax; o = p @ v(16x64)
// Pipeline: fused cast fp32->bf16 (query+W, one launch) -> MFMA GEMM (bf16, fp32 acc,
//           +bias, store bf16; 3 round-dispatches of 256 blocks = 1 block/CU each, for
//           per-round counter visibility; per-CU schedule identical to the single-768
//           dispatch which already executed as 3 sequential rounds) -> MFMA attention.
//
// GEMM (R1 schedule, best of 4 measured variants: ~105 us total, MfmaUtil 41%, 972 TF):
// 256x256 tile, BK=64, 8 waves (2M x 4N), 4-phase-per-K-tile pipelined schedule with
// counted vmcnt (never 0 in the main loop); barrier-pair per phase; i-outer epilogue
// (measured clean 98 MB WRITE_SIZE; j-outer measured 187 MB partial-line RMW).
//
// ATTENTION (MFMA, per position one wave, UNCONDITIONAL verified path):
//   QK: S = mfma_16x16x32_bf16(A=K, B=Q^T) x2  ->  S[g=grp*4+r][h=hn] in C-frag.
//   softmax over g: 3 fmax + shfl_xor(16,32); p = exp(s-m)/sum, bf16-packed (pa).
//   PV: O^T = V^T @ P via mfma_16x16x32_bf16 with zero-padded k>=16:
//     A-frag = V^T: lane(hn,grp) holds V[g=grp*8+j][db*16+hn] (8 ds_read_u16, rows
//              clamped to (grp&1)*8.. since k>=16 contributes zero);
//     B-frag = P:   lane(hn,grp) holds P[grp*8+j][hn] via 4 shfl from pa (src lanes
//              grp*32+hn, grp*32+16+hn — R4-verified mapping), zeroed for grp>=2;
//     C: lane holds o[h=hn][d=db*16+grp*4+r], r=0..3 -> 4x float4 stores (R5-verified).
//   No #if on the 16x16x16bf16_1k builtin: removes the silent-fallback uncertainty
//   (if the builtin was absent, R5 ran 16 scalar dword stores/lane).
// ws layout: Qb bf16 [16M el] @0 ; Wb bf16 [3M el] @33554432 ; QKVb bf16 [48M el] @39845888

typedef __attribute__((ext_vector_type(8))) short bf16x8;
typedef __attribute__((ext_vector_type(4))) short bf16x4;
typedef __attribute__((ext_vector_type(4))) float f32x4;

__device__ inline unsigned short f2bf(float f) {
  unsigned int i = __float_as_uint(f);
  i += 0x7fff + ((i >> 16) & 1);   // RNE
  return (unsigned short)(i >> 16);
}

__device__ inline void async16(const void* g, void* l) {
  __builtin_amdgcn_global_load_lds(
      (const __attribute__((address_space(1))) void*)g,
      (__attribute__((address_space(3))) void*)l, 16, 0, 0);
}

// ---------------- fused cast fp32 -> bf16 (query then W), 4 elems/thread ----------------
// n0 = 16777216 is a multiple of 1024 (block quantum), so no block straddles the seam.
__global__ __launch_bounds__(256) void cast2_kernel(const float* __restrict__ in0,
                                                    unsigned short* __restrict__ out0,
                                                    int n0,
                                                    const float* __restrict__ in1,
                                                    unsigned short* __restrict__ out1,
                                                    int n1) {
  int i = (blockIdx.x * 256 + threadIdx.x) * 4;
  const float* src; unsigned short* dst;
  if (i < n0) { src = in0 + i; dst = out0 + i; }
  else {
    int j = i - n0;
    if (j >= n1) return;
    src = in1 + j; dst = out1 + j;
  }
  float4 v = *(const float4*)src;
  union { unsigned short u[4]; unsigned long long ll; } o;
  o.u[0] = f2bf(v.x); o.u[1] = f2bf(v.y); o.u[2] = f2bf(v.z); o.u[3] = f2bf(v.w);
  *(unsigned long long*)dst = o.ll;
}

// ---------------- GEMM: C[M=16384][N=3072] = A[M][1024] * B[N][1024]^T + bias ----------------
#define GK 1024
#define GN 3072
__global__ __launch_bounds__(512, 2) void gemm_qkv(const unsigned short* __restrict__ A,
                                                   const unsigned short* __restrict__ Bm,
                                                   const float* __restrict__ bias,
                                                   unsigned short* __restrict__ C,
                                                   int base) {
  // double-buffered 256x64 tiles of A and B: 2 * 2 * 32 KiB = 128 KiB LDS
  __shared__ unsigned short As[2][256][64];
  __shared__ unsigned short Bs[2][256][64];

  // XCD-bijective swizzle over the full 768-block space (this dispatch covers
  // [base, base+256)), n-fast within each XCD chunk.
  const int bid = base + blockIdx.x;
  const int swz = (bid & 7) * 96 + (bid >> 3);
  const int m0 = (swz / 12) * 256;
  const int n0 = (swz % 12) * 256;

  const int tid  = threadIdx.x;
  const int lane = tid & 63;
  const int wave = tid >> 6;
  const int wm = wave & 1;        // 2 waves in M
  const int wn = wave >> 1;       // 4 waves in N
  const int fr = lane & 15;
  const int fq = lane >> 4;

  // staging geometry: slot = rho*512 + tid; row = slot>>3; chunk = (slot&7)^(row&7).
  const int r0 = tid >> 3;
  const int c0 = (tid & 7) ^ (r0 & 7);
  const unsigned short* gA = A  + (size_t)(m0 + r0) * GK + c0 * 8;
  const unsigned short* gB = Bm + (size_t)(n0 + r0) * GK + c0 * 8;
  const int ls0 = wave * 512;

#define STAGE_A(tt, hh) do {                                                   \
    unsigned short* lb_ = &As[(tt) & 1][(hh) * 128][0];                        \
    const unsigned short* g_ = gA + (size_t)(hh) * 128 * GK + (tt) * 64;       \
    async16(g_, lb_ + ls0);                                                    \
    async16(g_ + (size_t)64 * GK, lb_ + 4096 + ls0);                           \
  } while (0)
#define STAGE_B(tt, hh) do {                                                   \
    unsigned short* lb_ = &Bs[(tt) & 1][(hh) * 128][0];                        \
    const unsigned short* g_ = gB + (size_t)(hh) * 128 * GK + (tt) * 64;       \
    async16(g_, lb_ + ls0);                                                    \
    async16(g_ + (size_t)64 * GK, lb_ + 4096 + ls0);                           \
  } while (0)

  f32x4 acc[8][4] = {};

  // prologue: tile0 fully; tile1 all but A.h1 (that lands at W(0).p0) = 14 loads
  STAGE_A(0, 0); STAGE_A(0, 1); STAGE_B(0, 0); STAGE_B(0, 1);
  STAGE_B(1, 0); STAGE_A(1, 0); STAGE_B(1, 1);

  for (int t = 0; t < 16; ++t) {
    const int cur = t & 1;
    if (t == 0)       { asm volatile("s_waitcnt vmcnt(6)" ::: "memory"); }
    else if (t == 15) { asm volatile("s_waitcnt vmcnt(0)" ::: "memory"); }
    else              { asm volatile("s_waitcnt vmcnt(8)" ::: "memory"); }
    __builtin_amdgcn_s_barrier();
    __builtin_amdgcn_sched_barrier(0);

    bf16x8 bfr[4][2];
    #pragma unroll
    for (int p = 0; p < 4; ++p) {
      bf16x8 af[2][2];
      #pragma unroll
      for (int ii = 0; ii < 2; ++ii) {
        const int rA = (p * 2 + ii) * 32 + wm * 16 + fr;
        #pragma unroll
        for (int ks = 0; ks < 2; ++ks)
          af[ii][ks] = *(const bf16x8*)&As[cur][rA][((ks * 4 + fq) ^ (rA & 7)) * 8];
      }
      if (p == 0) {
        #pragma unroll
        for (int j = 0; j < 4; ++j) {
          const int rB = wn * 64 + j * 16 + fr;
          #pragma unroll
          for (int ks = 0; ks < 2; ++ks)
            bfr[j][ks] = *(const bf16x8*)&Bs[cur][rB][((ks * 4 + fq) ^ (rB & 7)) * 8];
        }
        if (t + 1 < 16) { STAGE_A(t + 1, 1); }
      }
      if (p == 1) {
        asm volatile("s_waitcnt vmcnt(8)" ::: "memory");
      }
      if (p == 2 && t + 2 < 16) { STAGE_B(t + 2, 0); }
      if (p == 3 && t + 2 < 16) { STAGE_A(t + 2, 0); STAGE_B(t + 2, 1); }

      __builtin_amdgcn_s_barrier();
      __builtin_amdgcn_sched_barrier(0);
      __builtin_amdgcn_s_setprio(1);
      #pragma unroll
      for (int ks = 0; ks < 2; ++ks)
        #pragma unroll
        for (int ii = 0; ii < 2; ++ii)
          #pragma unroll
          for (int j = 0; j < 4; ++j)
            acc[p * 2 + ii][j] = __builtin_amdgcn_mfma_f32_16x16x32_bf16(
                af[ii][ks], bfr[j][ks], acc[p * 2 + ii][j], 0, 0, 0);
      __builtin_amdgcn_s_setprio(0);
      __builtin_amdgcn_sched_barrier(0);
    }
  }
#undef STAGE_A
#undef STAGE_B

  // epilogue: bias + bf16 store; i-outer (measured 98 MB WRITE_SIZE; j-outer was 187 MB)
  #pragma unroll
  for (int i = 0; i < 8; ++i) {
    #pragma unroll
    for (int j = 0; j < 4; ++j) {
      const int col = n0 + wn * 64 + j * 16 + fr;
      const float bc = bias[col];
      const int rowb = m0 + i * 32 + wm * 16 + fq * 4;
      #pragma unroll
      for (int rr = 0; rr < 4; ++rr)
        C[(size_t)(rowb + rr) * GN + col] = f2bf(acc[i][j][rr] + bc);
    }
  }
}

// ---------------- per-position MFMA attention ----------------
// one wave per position.  hn = lane&15, grp = lane>>4.
__global__ __launch_bounds__(256, 4) void attn_kernel(const unsigned short* __restrict__ QKV,
                                                      const float* __restrict__ mask,
                                                      float* __restrict__ out) {
  __shared__ unsigned short shV[4][1024];   // per wave: V [16 g][64 d] bf16, linear
  const int wave = threadIdx.x >> 6;
  const int lane = threadIdx.x & 63;
  const int pos = blockIdx.x * 4 + wave;

  const unsigned short* row = QKV + (size_t)pos * 3072;

  // ---- stage V (1024 bf16 = 2 KB) via 2 DMA chunks (wave-private, no barrier)
  async16(&row[2048 + (size_t)lane * 8], &shV[wave][0]);
  async16(&row[2048 + 512 + (size_t)lane * 8], &shV[wave][512]);

  const int hn  = lane & 15;    // h for QK (B n-index / C col); m-low for PV A-frag
  const int grp = lane >> 4;    // k-group

  // ---- Q B-frag / K A-frag: per-lane 16B contiguous, straight from global
  const int qk_off = hn * 64 + grp * 8;
  bf16x8 qf0 = *(const bf16x8*)&row[qk_off];             // q[h=hn][d: grp*8..+8)
  bf16x8 qf1 = *(const bf16x8*)&row[qk_off + 32];        // d: 32+grp*8..
  bf16x8 kf0 = *(const bf16x8*)&row[1024 + qk_off];      // k[g=hn][d: grp*8..+8)
  bf16x8 kf1 = *(const bf16x8*)&row[1024 + qk_off + 32];

  // ---- mask[pos][h=hn][g=grp*4 + i]: one coalesced float4 per lane
  float4 mk = *(const float4*)&mask[(size_t)pos * 256 + hn * 16 + grp * 4];

  // ---- S[g][h] = sum_d k[g][d] q[h][d]
  f32x4 s = {};
  s = __builtin_amdgcn_mfma_f32_16x16x32_bf16(kf0, qf0, s, 0, 0, 0);
  s = __builtin_amdgcn_mfma_f32_16x16x32_bf16(kf1, qf1, s, 0, 0, 0);

  // ---- softmax over g (rows): lane holds s[g=grp*4+r][h=hn], r=0..3
  float sv0 = s[0] * 0.125f + mk.x;
  float sv1 = s[1] * 0.125f + mk.y;
  float sv2 = s[2] * 0.125f + mk.z;
  float sv3 = s[3] * 0.125f + mk.w;
  float mx = fmaxf(fmaxf(sv0, sv1), fmaxf(sv2, sv3));
  mx = fmaxf(mx, __shfl_xor(mx, 16));
  mx = fmaxf(mx, __shfl_xor(mx, 32));
  float p0 = __expf(sv0 - mx), p1 = __expf(sv1 - mx);
  float p2 = __expf(sv2 - mx), p3 = __expf(sv3 - mx);
  float sum = p0 + p1 + p2 + p3;
  sum += __shfl_xor(sum, 16);
  sum += __shfl_xor(sum, 32);
  const float inv = 1.f / sum;

  // ---- pack P*(1/sum) -> bf16 (element j at lane (hn,grp) = P[g=grp*4+j][h=hn])
  union { unsigned u[2]; bf16x4 v; } pa;
  pa.u[0] = (unsigned)f2bf(p0 * inv) | ((unsigned)f2bf(p1 * inv) << 16);
  pa.u[1] = (unsigned)f2bf(p2 * inv) | ((unsigned)f2bf(p3 * inv) << 16);

  // ---- PV B-frag = P[k=grp*8+j][n=hn] via 4 shfl (R4-verified lane mapping);
  //      zero for grp>=2 (k >= 16 is padding).
  const int src = grp * 32 + hn;
  unsigned b0 = __shfl((int)pa.u[0], src),      b1 = __shfl((int)pa.u[1], src);
  unsigned b2 = __shfl((int)pa.u[0], src + 16), b3 = __shfl((int)pa.u[1], src + 16);
  if (grp >= 2) { b0 = b1 = b2 = b3 = 0; }
  union { unsigned u[4]; bf16x8 v; } pb;
  pb.u[0] = b0; pb.u[1] = b1; pb.u[2] = b2; pb.u[3] = b3;

  asm volatile("s_waitcnt vmcnt(0)" ::: "memory");   // V DMA complete (oldest in queue)

  // ---- PV: O^T = V^T @ P.  A-frag: lane holds A[m=hn][k=grp*8+j] = V[g][db*16+hn];
  //      rows for grp>=2 are k>=16 padding (x0) -> clamp to (grp&1)*8.. (in-bounds).
  const unsigned short* va = &shV[wave][(grp & 1) * 8 * 64];
  #pragma unroll
  for (int db = 0; db < 4; ++db) {
    const int e0 = db * 16 + hn;
    union { unsigned u[4]; bf16x8 v; } av;
    #pragma unroll
    for (int jj = 0; jj < 4; ++jj) {
      unsigned lo = va[(2 * jj) * 64 + e0];
      unsigned hi = va[(2 * jj + 1) * 64 + e0];
      av.u[jj] = lo | (hi << 16);
    }
    f32x4 z = {};
    f32x4 o4 = __builtin_amdgcn_mfma_f32_16x16x32_bf16(av.v, pb.v, z, 0, 0, 0);
    // C: lane holds o[h=hn][d = db*16 + grp*4 + r], r=0..3 -> one float4 store
    *(float4*)(out + (size_t)pos * 1024 + hn * 64 + db * 16 + grp * 4) =
        *(const float4*)&o4;
  }
}

extern "C" void kernel_launch(void* const* d_in, const int* in_sizes, int n_in,
                              void* d_out, int out_size, void* d_ws, size_t ws_size,
                              hipStream_t stream) {
  const float* query = (const float*)d_in[0];
  // d_in[1] (key) and d_in[2] (value) are unused by the reference.
  const float* mask  = (const float*)d_in[3];
  const float* Wqkv  = (const float*)d_in[4];
  const float* bqkv  = (const float*)d_in[5];
  float* out = (float*)d_out;

  unsigned short* qb   = (unsigned short*)d_ws;                                  // 16,777,216 el
  unsigned short* wb   = (unsigned short*)((char*)d_ws + 33554432);              //  3,145,728 el
  unsigned short* qkvb = (unsigned short*)((char*)d_ws + 39845888);              // 50,331,648 el

  cast2_kernel<<<19456, 256, 0, stream>>>(query, qb, 16777216, Wqkv, wb, 3145728);

  // 3 round-dispatches of 256 blocks (1 block/CU each): per-CU schedule identical to
  // the single 768-block dispatch; gives per-round counter visibility.
  gemm_qkv<<<256, 512, 0, stream>>>(qb, wb, bqkv, qkvb, 0);
  gemm_qkv<<<256, 512, 0, stream>>>(qb, wb, bqkv, qkvb, 256);
  gemm_qkv<<<256, 512, 0, stream>>>(qb, wb, bqkv, qkvb, 512);

  attn_kernel<<<4096, 256, 0, stream>>>(qkvb, mask, out);
}